// Round 11
// baseline (446.448 us; speedup 1.0000x reference)
//
#include <hip/hip_runtime.h>
#include <hip/hip_bf16.h>

#define NN 512
#define DEG 8
#define FD 128
#define HD 256
#define MD 256
#define OD 64
#define PD 2
#define HIST 10
#define TOTAL (10 * NN)       /* 5120 queue entries processed */
#define NPAR 648              /* entries with children: i < (TOTAL-S)/8 <= 632 */
#define INV_SQRT_H 0.0625f

typedef __hip_bfloat16 bf16;

// bit-level finite guard (fast-math-proof)
__device__ __forceinline__ float finz(float x) {
  unsigned u = __float_as_uint(x);
  return (((u >> 23) & 0xFFu) == 0xFFu) ? 0.f : x;
}

// runtime-dtype load: bf=1 -> bf16 array, bf=0 -> float array
__device__ __forceinline__ float ldin(const void* p, int idx, int bf) {
  if (bf) return __bfloat162float(((const bf16*)p)[idx]);
  return ((const float*)p)[idx];
}

// device-coherent dword load/store (relaxed agent atomics -> flagged global op,
// bypasses non-coherent L2 for THIS access only; no cache-wide fences anywhere)
__device__ __forceinline__ float scload(const float* p) {
  return __uint_as_float(__hip_atomic_load((const unsigned*)p, __ATOMIC_RELAXED,
                                           __HIP_MEMORY_SCOPE_AGENT));
}
__device__ __forceinline__ void scstore(float* p, float v) {
  __hip_atomic_store((unsigned*)p, __float_as_uint(v), __ATOMIC_RELAXED,
                     __HIP_MEMORY_SCOPE_AGENT);
}

// ---- static device scratch ----
__device__ float g_hist[NN * HIST * HD];    // slot-0 encoded states (k_prep -> k_flow)
__device__ float g_msgb[NPAR * MD];         // messages of entries with children
__device__ float g_WQK[HD * HD];            // Wq @ Wk^T   (kq = msg.WQK + ck)
__device__ float g_WrS[HD * HD];            // sum of 4 Wr row-blocks
__device__ float g_vq[HD];                  // Wq @ bk
__device__ float g_ck[HD];                  // Wk @ bq
__device__ float g_bqk;                     // bq . bk
__device__ int   g_node[TOTAL];
__device__ int   g_done[TOTAL];             // message-ready flags (parents only)
__device__ int   g_dtype;                   // 1 = float tensors are bf16
__device__ int   g_i64;                     // 1 = neighbors int64

__device__ __forceinline__ int decode_S(const int* dS) {
  int r = dS[0];
  if (r >= 1 && r <= NN) return r;
  float f = __int_as_float(r);
  if (f >= 1.f && f <= (float)NN) return (int)f;
  unsigned u = ((unsigned)r & 0xFFFFu) << 16;
  float g = __uint_as_float(u);
  if (g >= 1.f && g <= (float)NN) return (int)g;
  return 64;
}

__device__ __forceinline__ int get_nbr(const int* nbrs, int i64, int n, int d) {
  int v = i64 ? nbrs[2 * (n * DEG + d)] : nbrs[n * DEG + d];
  return (v < 0) ? 0 : (v >= NN ? NN - 1 : v);
}

// wave-parallel dtype probe: same predicate as the validated serial version,
// one ballot over the first 64 words instead of 64 serial loads.
__device__ __forceinline__ int detect_bf(const unsigned* xa_w) {
  const int lane = threadIdx.x & 63;
  unsigned lo = xa_w[lane] & 0xFFFFu;
  float av = fabsf(__uint_as_float(lo << 16));
  unsigned long long m = __ballot(av > 0.000244140625f && av < 64.f);
  return ((int)__popcll(m) >= 32) ? 1 : 0;
}

// ---------------- k_prep: weights fold + encode + BFS, ONE dispatch -----------------
// blocks 0..HD-1: WQK/WrS/vq rows; HD: ck/bqk; HD+1..HD+NN: encode; HD+NN+1: BFS.
// Wk access is LDS-staged (round 10): global reads coalesced, transpose via LDS tile.
__global__ void __launch_bounds__(1024)
k_prep(const void* __restrict__ xa, const unsigned* __restrict__ xa_w,
       const int* __restrict__ nbrs, const int* __restrict__ dS,
       const void* __restrict__ We, const void* __restrict__ be,
       const void* __restrict__ Wq, const void* __restrict__ Wk,
       const void* __restrict__ Wr, const void* __restrict__ bq,
       const void* __restrict__ bk) {
  const int b = blockIdx.x, t = threadIdx.x;
  const int col = t & 255, grp = t >> 8;
  const int wave = t >> 6, lane = t & 63;
  const int bf = detect_bf(xa_w);
  if (t < 8) { int fi = 8 * b + t; if (fi < TOTAL) g_done[fi] = 0; }
  __shared__ float sw[HD];
  __shared__ float sp[4][HD];
  __shared__ float sr[16];
  __shared__ float s_wkT[32][HD + 1];        // Wk^T tile, 32.9 KB, conflict-free
  __shared__ int s_node[TOTAL];              // BFS block only (20 KB)
  if (b < HD) {
    if (grp == 0) sw[col] = ldin(Wq, b * HD + col, bf);
    __syncthreads();
    if (grp == 1) {                              // vq[b] partial (overlapped)
      float pv = sw[col] * ldin(bk, col, bf);
#pragma unroll
      for (int off = 32; off > 0; off >>= 1) pv += __shfl_down(pv, off, 64);
      if (lane == 0) sr[wave] = pv;              // waves 4..7
    }
    if (grp == 2) {                              // WrS row b (overlapped, coalesced)
      float s = 0.f;
#pragma unroll
      for (int q = 0; q < 4; ++q) s += ldin(Wr, (size_t)(q * HD + b) * HD + col, bf);
      g_WrS[b * HD + col] = s;
    }
    // WQK[b][col] = Wq row b . Wk row col, via LDS-staged Wk^T tiles
    float acc0 = 0.f, acc1 = 0.f;
    const int hh = t & 31, r0 = t >> 5;          // staging coords (r0: 0..31)
    for (int h0 = 0; h0 < HD; h0 += 32) {
#pragma unroll
      for (int rr = 0; rr < 8; ++rr) {           // coalesced: hh is the fast axis
        const int row = rr * 32 + r0;
        s_wkT[hh][row] = ldin(Wk, row * HD + h0 + hh, bf);
      }
      __syncthreads();
      const int hb = grp * 8;                    // grp's 8-slice of this tile
#pragma unroll
      for (int i = 0; i < 8; i += 2) {
        acc0 += sw[h0 + hb + i]     * s_wkT[hb + i][col];
        acc1 += sw[h0 + hb + i + 1] * s_wkT[hb + i + 1][col];
      }
      __syncthreads();                           // tile reuse guard
    }
    sp[grp][col] = acc0 + acc1;
    __syncthreads();
    if (grp == 0)
      g_WQK[b * HD + col] = (sp[0][col] + sp[1][col]) + (sp[2][col] + sp[3][col]);
    if (t == 0) g_vq[b] = (sr[4] + sr[5]) + (sr[6] + sr[7]);
  } else if (b == HD) {
    {                                            // ck[col] = Wk row col . bq, split 4
      const int h0 = grp * 64;
      float a0 = 0.f, a1 = 0.f, a2 = 0.f, a3 = 0.f;
      for (int h = 0; h < 64; h += 4) {
        a0 += ldin(Wk, col * HD + h0 + h,     bf) * ldin(bq, h0 + h,     bf);
        a1 += ldin(Wk, col * HD + h0 + h + 1, bf) * ldin(bq, h0 + h + 1, bf);
        a2 += ldin(Wk, col * HD + h0 + h + 2, bf) * ldin(bq, h0 + h + 2, bf);
        a3 += ldin(Wk, col * HD + h0 + h + 3, bf) * ldin(bq, h0 + h + 3, bf);
      }
      sp[grp][col] = (a0 + a1) + (a2 + a3);
    }
    if (grp == 1) {
      float pb = ldin(bq, col, bf) * ldin(bk, col, bf);
#pragma unroll
      for (int off = 32; off > 0; off >>= 1) pb += __shfl_down(pb, off, 64);
      if (lane == 0) sr[wave] = pb;              // waves 4..7
    }
    __syncthreads();
    if (grp == 0)
      g_ck[col] = (sp[0][col] + sp[1][col]) + (sp[2][col] + sp[3][col]);
    if (t == 0) g_bqk = (sr[4] + sr[5]) + (sr[6] + sr[7]);
  } else if (b <= HD + NN) {                     // encode node n, K=FD split 4
    const int n = b - HD - 1;
    if (t < FD) sw[t] = ldin(xa, n * FD + t, bf);
    __syncthreads();
    const int f0 = grp * 32;
    float a0 = 0.f, a1 = 0.f, a2 = 0.f, a3 = 0.f;
    for (int f = 0; f < 32; f += 4) {
      a0 += sw[f0 + f]     * ldin(We, (f0 + f)     * HD + col, bf);
      a1 += sw[f0 + f + 1] * ldin(We, (f0 + f + 1) * HD + col, bf);
      a2 += sw[f0 + f + 2] * ldin(We, (f0 + f + 2) * HD + col, bf);
      a3 += sw[f0 + f + 3] * ldin(We, (f0 + f + 3) * HD + col, bf);
    }
    sp[grp][col] = (a0 + a1) + (a2 + a3);
    __syncthreads();
    if (grp == 0)
      g_hist[(size_t)(n * HIST) * HD + col] =
          ldin(be, col, bf) + (sp[0][col] + sp[1][col]) + (sp[2][col] + sp[3][col]);
  } else {                                       // BFS queue expansion
    if (t == 0) g_dtype = bf;
    bool c8 = (lane < 8) ? (nbrs[2 * lane + 1] == 0) : true;
    unsigned long long im = __ballot(c8);
    const int i64 = ((im & 0xFFull) == 0xFFull) ? 1 : 0;
    if (t == 0) g_i64 = i64;
    const int S = decode_S(dS);
    for (int i = t; i < S; i += 1024) s_node[i] = i;
    __syncthreads();
    int done = S;
    while (done < TOTAL) {                       // message tree, depth ~4
      long long nd = (long long)S + 8LL * (long long)done;
      int new_done = nd > (long long)TOTAL ? TOTAL : (int)nd;
      for (int i = done + t; i < new_done; i += 1024)
        s_node[i] = get_nbr(nbrs, i64, s_node[(i - S) >> 3], (i - S) & 7);
      __syncthreads();
      done = new_done;
    }
    for (int i = t; i < TOTAL; i += 1024) g_node[i] = s_node[i];
  }
}

// ---------------- dataflow executor: ONE BLOCK PER NODE + fused output --------------
// Round-8 proven body + NEW cross-step kq fusion: when the next entry's message is
// prefetched (block-uniform dopf), it is committed to LDS before the s_vals barrier
// and next step's kq = msg'.WQK is computed FUSED with this step's ns = vals.WrS
// (two independent load streams -> 2x loads in flight, same serial length). The next
// step then skips its kq matvec (kq carried in a register; identical summation
// pattern -> bitwise-same numerics).
// Residency: 512 blocks, launch_bounds(256,2), ~35 KB LDS -> 2 blocks/CU = all 512
// resident. Deps of entry e have smaller queue index -> progress by induction.
__global__ void __launch_bounds__(256, 2)
k_flow(const void* __restrict__ fmsg, const void* __restrict__ br_,
       const void* __restrict__ Wm, const void* __restrict__ bm,
       const void* __restrict__ Wd, const void* __restrict__ bd,
       void* __restrict__ out, const int* __restrict__ dS) {
  const int n = blockIdx.x;
  const int t = threadIdx.x;
  const int wave = t >> 6, lane = t & 63;
  const int S = decode_S(dS);
  const int bf = g_dtype;
  __shared__ float s_hist[HIST][HD];         // node-n ring buffer, column t private
  __shared__ float s_msgb2[2][MD];           // double-buffered message
  __shared__ float s_vals[HD];
  __shared__ float s_ns[HD];
  __shared__ float s_red[4][HIST + 1];
  __shared__ int   s_list[TOTAL];            // safe upper bound (20 KB)
  __shared__ int   s_cnt;
  __shared__ int   s_pf[2];                  // prefetch-done flag per buffer parity

  // loop invariants in registers
  const float rck = g_ck[t];
  const float rvq = g_vq[t];
  const float rbqk = g_bqk;
  const float rbr = ldin(br_, t, bf);
  const float rbm = ldin(bm, t, bf);

#pragma unroll
  for (int j = 1; j < HIST; ++j) s_hist[j][t] = 0.f;   // invalid slots read as 0
  s_hist[0][t] = finz(g_hist[(size_t)n * HIST * HD + t]);  // encoded state

  if (wave == 0) {                           // build node-n entry list (queue order)
    int k = 0;
    for (int base = 0; base < TOTAL; base += 64) {
      int nd = g_node[base + lane];
      unsigned long long m = __ballot(nd == n);
      if (nd == n) {
        unsigned long long below = m & ((1ull << lane) - 1ull);
        s_list[k + (int)__popcll(below)] = base + lane;
      }
      k += (int)__popcll(m);
    }
    if (lane == 0) { s_cnt = k; s_pf[0] = 0; s_pf[1] = 0; }
  }
  __syncthreads();
  const int cnt = s_cnt;

  float kqc = 0.f;                           // carried next-step kq (valid iff havepf)
  for (int k = 0; k < cnt; ++k) {
    const int e = s_list[k];
    const int c = k + 1;
    const int v = (c < HIST) ? c : HIST;
    const int slot = c % HIST;
    const bool hc = (S + 8 * e) < TOTAL;
    float* s_msg = s_msgb2[k & 1];
    const int havepf = s_pf[k & 1];          // written by t0 last step; end barrier

    // t0: decide prefetch for k+1 (flag may flip later -> blocking path catches it)
    if (t == 0) {
      int pf = 0;
      if (k + 1 < cnt) {
        const int e2 = s_list[k + 1];
        if (e2 < S) pf = 1;
        else pf = (__hip_atomic_load(&g_done[(e2 - S) >> 3], __ATOMIC_RELAXED,
                                     __HIP_MEMORY_SCOPE_AGENT) != 0);
      }
      s_pf[(k + 1) & 1] = pf;
    }

    float kq;
    if (havepf) {
      kq = kqc;                              // computed in last step's fused loop
    } else {
      // ---- acquire message ----
      if (e < S) {
        s_msg[t] = finz(ldin(fmsg, e * MD + t, bf));
      } else {
        const int p = (e - S) >> 3;
        if (t == 0)
          while (__hip_atomic_load(&g_done[p], __ATOMIC_RELAXED,
                                   __HIP_MEMORY_SCOPE_AGENT) == 0)
            __builtin_amdgcn_s_sleep(4);
        __syncthreads();                     // flag seen by whole block
        s_msg[t] = finz(scload(g_msgb + (size_t)p * MD + t));
      }
      __syncthreads();
      // ---- kq[t] = msg . WQK[:,t] + ck[t] (4-acc, proven scalar walk) ----
      float a0 = 0.f, a1 = 0.f, a2 = 0.f, a3 = 0.f;
      for (int m = 0; m < MD; m += 4) {
        a0 += s_msg[m]     * g_WQK[(m)     * HD + t];
        a1 += s_msg[m + 1] * g_WQK[(m + 1) * HD + t];
        a2 += s_msg[m + 2] * g_WQK[(m + 2) * HD + t];
        a3 += s_msg[m + 3] * g_WQK[(m + 3) * HD + t];
      }
      kq = rck + ((a0 + a1) + (a2 + a3));
    }

    // ---- 11 dot-products via wave shuffle + LDS fold ----
    float part[HIST + 1];
#pragma unroll
    for (int j = 0; j < HIST; ++j) part[j] = s_hist[j][t] * kq;
    part[HIST] = s_msg[t] * rvq;
#pragma unroll
    for (int o = 32; o > 0; o >>= 1) {
#pragma unroll
      for (int j = 0; j <= HIST; ++j) part[j] += __shfl_down(part[j], o, 64);
    }
    if (lane == 0) {
#pragma unroll
      for (int j = 0; j <= HIST; ++j) s_red[wave][j] = part[j];
    }
    __syncthreads();                         // scores-fold barrier (s_pf visible too)

    // ---- issue next-message prefetch into a register ----
    const int dopf = s_pf[(k + 1) & 1];
    float pm = 0.f;
    if (dopf) {
      const int e2 = s_list[k + 1];
      pm = (e2 < S) ? ldin(fmsg, e2 * MD + t, bf)
                    : scload(g_msgb + (size_t)((e2 - S) >> 3) * MD + t);
    }

    float sc[HIST + 1];
#pragma unroll
    for (int j = 0; j <= HIST; ++j)
      sc[j] = (s_red[0][j] + s_red[1][j]) + (s_red[2][j] + s_red[3][j]);
    const float bkq = sc[HIST] + rbqk;
    float lg[HIST];
#pragma unroll
    for (int j = 0; j < HIST; ++j)
      lg[j] = (j < v) ? ((sc[j] + bkq) * INV_SQRT_H) : -1e30f;
    float mx = lg[0];
#pragma unroll
    for (int j = 1; j < HIST; ++j) mx = fmaxf(mx, lg[j]);
    float e_[HIST], den = 0.f;
#pragma unroll
    for (int j = 0; j < HIST; ++j) { e_[j] = __expf(lg[j] - mx); den += e_[j]; }
    const float iden = 1.0f / den;
    float val = 0.f;
#pragma unroll
    for (int j = 0; j < HIST; ++j) val += e_[j] * s_hist[j][t];
    s_vals[t] = val * iden;
    if (dopf) s_msgb2[(k + 1) & 1][t] = finz(pm);  // commit BEFORE barrier (pm latency
                                                   // hidden under softmax VALU above)
    __syncthreads();                         // s_vals + next msg visible

    // ---- ns = vals @ WrS + br; fused with next-step kq when prefetch hit ----
    float ns;
    if (dopf) {
      const float* nm = s_msgb2[(k + 1) & 1];
      float b0 = 0.f, b1 = 0.f, b2 = 0.f, b3 = 0.f;
      float ka0 = 0.f, ka1 = 0.f, ka2 = 0.f, ka3 = 0.f;
      for (int h = 0; h < HD; h += 4) {
        b0  += s_vals[h]     * g_WrS[(h)     * HD + t];
        b1  += s_vals[h + 1] * g_WrS[(h + 1) * HD + t];
        b2  += s_vals[h + 2] * g_WrS[(h + 2) * HD + t];
        b3  += s_vals[h + 3] * g_WrS[(h + 3) * HD + t];
        ka0 += nm[h]         * g_WQK[(h)     * HD + t];
        ka1 += nm[h + 1]     * g_WQK[(h + 1) * HD + t];
        ka2 += nm[h + 2]     * g_WQK[(h + 2) * HD + t];
        ka3 += nm[h + 3]     * g_WQK[(h + 3) * HD + t];
      }
      ns = rbr + ((b0 + b1) + (b2 + b3));
      kqc = rck + ((ka0 + ka1) + (ka2 + ka3));
    } else {
      float b0 = 0.f, b1 = 0.f, b2 = 0.f, b3 = 0.f;
      for (int h = 0; h < HD; h += 4) {
        b0 += s_vals[h]     * g_WrS[(h)     * HD + t];
        b1 += s_vals[h + 1] * g_WrS[(h + 1) * HD + t];
        b2 += s_vals[h + 2] * g_WrS[(h + 2) * HD + t];
        b3 += s_vals[h + 3] * g_WrS[(h + 3) * HD + t];
      }
      ns = rbr + ((b0 + b1) + (b2 + b3));
    }
    s_hist[slot][t] = ns;                    // column-private
    if (hc) s_ns[t] = ns;
    __syncthreads();                         // s_ns visible to all waves

    // ---- newmessage = [ns; msg] @ Wm + bm (parents only) ----
    if (hc) {
      float c0 = 0.f, c1 = 0.f, c2 = 0.f, c3 = 0.f;
      if (bf) {
        const bf16* w = (const bf16*)Wm;
        for (int h = 0; h < HD; h += 4) {
          c0 += s_ns[h]     * __bfloat162float(w[(h)     * MD + t]);
          c1 += s_ns[h + 1] * __bfloat162float(w[(h + 1) * MD + t]);
          c2 += s_ns[h + 2] * __bfloat162float(w[(h + 2) * MD + t]);
          c3 += s_ns[h + 3] * __bfloat162float(w[(h + 3) * MD + t]);
        }
        for (int m = 0; m < MD; m += 4) {
          c0 += s_msg[m]     * __bfloat162float(w[(HD + m)     * MD + t]);
          c1 += s_msg[m + 1] * __bfloat162float(w[(HD + m + 1) * MD + t]);
          c2 += s_msg[m + 2] * __bfloat162float(w[(HD + m + 2) * MD + t]);
          c3 += s_msg[m + 3] * __bfloat162float(w[(HD + m + 3) * MD + t]);
        }
      } else {
        const float* w = (const float*)Wm;
        for (int h = 0; h < HD; h += 4) {
          c0 += s_ns[h]     * w[(h)     * MD + t];
          c1 += s_ns[h + 1] * w[(h + 1) * MD + t];
          c2 += s_ns[h + 2] * w[(h + 2) * MD + t];
          c3 += s_ns[h + 3] * w[(h + 3) * MD + t];
        }
        for (int m = 0; m < MD; m += 4) {
          c0 += s_msg[m]     * w[(HD + m)     * MD + t];
          c1 += s_msg[m + 1] * w[(HD + m + 1) * MD + t];
          c2 += s_msg[m + 2] * w[(HD + m + 2) * MD + t];
          c3 += s_msg[m + 3] * w[(HD + m + 3) * MD + t];
        }
      }
      scstore(&g_msgb[(size_t)e * MD + t], rbm + ((c0 + c1) + (c2 + c3)));
      asm volatile("s_waitcnt vmcnt(0)" ::: "memory");   // own store at coherence pt
    }
    __syncthreads();                         // stores drained + LDS reuse guard
    if (hc && t == 0)
      __hip_atomic_store(&g_done[e], 1, __ATOMIC_RELAXED,
                         __HIP_MEMORY_SCOPE_AGENT);
  }

  // ---- fused final projection + log_softmax (threads 0..127: pp = t>>6, o = t&63) --
  const int slotF = cnt % HIST;
  if (t < PD * OD) {
    const int pp = t >> 6, o = t & 63;
    float acc = finz(ldin(bd, pp * OD + o, bf));
    for (int h = 0; h < HD; ++h)
      acc += finz(s_hist[slotF][h]) * ldin(Wd, (pp * HD + h) * OD + o, bf);
    acc = finz(acc);
    float mx = acc;
#pragma unroll
    for (int off = 32; off > 0; off >>= 1) mx = fmaxf(mx, __shfl_xor(mx, off, 64));
    float ex = __expf(acc - mx);
    float s = ex;
#pragma unroll
    for (int off = 32; off > 0; off >>= 1) s += __shfl_xor(s, off, 64);
    float r = finz(acc - mx - logf(s));
    const int oi = (pp * NN + n) * OD + o;
    if (bf) ((bf16*)out)[oi] = __float2bfloat16(r);
    else    ((float*)out)[oi] = r;
  }
}

extern "C" void kernel_launch(void* const* d_in, const int* in_sizes, int n_in,
                              void* d_out, int out_size, void* d_ws, size_t ws_size,
                              hipStream_t stream) {
  const void* xa   = d_in[0];
  const int*  nbrs = (const int*)d_in[1];
  const void* fmsg = d_in[2];
  const void* We   = d_in[3];
  const void* be   = d_in[4];
  const void* Wq   = d_in[5];
  const void* bq   = d_in[6];
  const void* Wk   = d_in[7];
  const void* bk   = d_in[8];
  const void* Wr   = d_in[9];
  const void* br   = d_in[10];
  const void* Wm   = d_in[11];
  const void* bm   = d_in[12];
  const void* Wd   = d_in[13];
  const void* bd   = d_in[14];
  const int*  dS   = (const int*)d_in[15];
  (void)d_ws; (void)ws_size; (void)in_sizes; (void)n_in; (void)out_size;

  k_prep<<<dim3(HD + 1 + NN + 1), dim3(1024), 0, stream>>>(
      xa, (const unsigned*)xa, nbrs, dS, We, be, Wq, Wk, Wr, bq, bk);
  k_flow<<<dim3(NN), dim3(256), 0, stream>>>(fmsg, br, Wm, bm, Wd, bd, d_out, dS);
}

// Round 12
// 437.753 us; speedup vs baseline: 1.0199x; 1.0199x over previous
//
#include <hip/hip_runtime.h>
#include <hip/hip_bf16.h>

#define NN 512
#define DEG 8
#define FD 128
#define HD 256
#define MD 256
#define OD 64
#define PD 2
#define HIST 10
#define TOTAL (10 * NN)       /* 5120 queue entries processed */
#define NPAR 648              /* entries with children: i < (TOTAL-S)/8 <= 632 */
#define INV_SQRT_H 0.0625f

typedef __hip_bfloat16 bf16;

// bit-level finite guard (fast-math-proof)
__device__ __forceinline__ float finz(float x) {
  unsigned u = __float_as_uint(x);
  return (((u >> 23) & 0xFFu) == 0xFFu) ? 0.f : x;
}

// runtime-dtype load: bf=1 -> bf16 array, bf=0 -> float array
__device__ __forceinline__ float ldin(const void* p, int idx, int bf) {
  if (bf) return __bfloat162float(((const bf16*)p)[idx]);
  return ((const float*)p)[idx];
}

// device-coherent dword load/store (relaxed agent atomics -> flagged global op,
// bypasses non-coherent L2 for THIS access only; no cache-wide fences anywhere)
__device__ __forceinline__ float scload(const float* p) {
  return __uint_as_float(__hip_atomic_load((const unsigned*)p, __ATOMIC_RELAXED,
                                           __HIP_MEMORY_SCOPE_AGENT));
}
__device__ __forceinline__ void scstore(float* p, float v) {
  __hip_atomic_store((unsigned*)p, __float_as_uint(v), __ATOMIC_RELAXED,
                     __HIP_MEMORY_SCOPE_AGENT);
}

// ---- static device scratch ----
__device__ float g_hist[NN * HIST * HD];    // slot-0 encoded states (k_prep -> k_flow)
__device__ float g_msgb[NPAR * MD];         // messages of entries with children
__device__ float g_WQK[HD * HD];            // Wq @ Wk^T   (kq = msg.WQK + ck)
__device__ float g_WrS[HD * HD];            // sum of 4 Wr row-blocks
__device__ float g_vq[HD];                  // Wq @ bk
__device__ float g_ck[HD];                  // Wk @ bq
__device__ float g_bqk;                     // bq . bk
__device__ int   g_node[TOTAL];
__device__ int   g_done[TOTAL];             // message-ready flags (parents only)
__device__ int   g_dtype;                   // 1 = float tensors are bf16
__device__ int   g_i64;                     // 1 = neighbors int64

__device__ __forceinline__ int decode_S(const int* dS) {
  int r = dS[0];
  if (r >= 1 && r <= NN) return r;
  float f = __int_as_float(r);
  if (f >= 1.f && f <= (float)NN) return (int)f;
  unsigned u = ((unsigned)r & 0xFFFFu) << 16;
  float g = __uint_as_float(u);
  if (g >= 1.f && g <= (float)NN) return (int)g;
  return 64;
}

__device__ __forceinline__ int get_nbr(const int* nbrs, int i64, int n, int d) {
  int v = i64 ? nbrs[2 * (n * DEG + d)] : nbrs[n * DEG + d];
  return (v < 0) ? 0 : (v >= NN ? NN - 1 : v);
}

// wave-parallel dtype probe: same predicate as the validated serial version,
// one ballot over the first 64 words instead of 64 serial loads.
__device__ __forceinline__ int detect_bf(const unsigned* xa_w) {
  const int lane = threadIdx.x & 63;
  unsigned lo = xa_w[lane] & 0xFFFFu;
  float av = fabsf(__uint_as_float(lo << 16));
  unsigned long long m = __ballot(av > 0.000244140625f && av < 64.f);
  return ((int)__popcll(m) >= 32) ? 1 : 0;
}

// ---------------- k_prep: weights fold + encode + BFS, ONE dispatch -----------------
// blocks 0..HD-1: WQK/WrS/vq rows; HD: ck/bqk; HD+1..HD+NN: encode; HD+NN+1: BFS.
// Wk access is LDS-staged (round 10): global reads coalesced, transpose via LDS tile.
__global__ void __launch_bounds__(1024)
k_prep(const void* __restrict__ xa, const unsigned* __restrict__ xa_w,
       const int* __restrict__ nbrs, const int* __restrict__ dS,
       const void* __restrict__ We, const void* __restrict__ be,
       const void* __restrict__ Wq, const void* __restrict__ Wk,
       const void* __restrict__ Wr, const void* __restrict__ bq,
       const void* __restrict__ bk) {
  const int b = blockIdx.x, t = threadIdx.x;
  const int col = t & 255, grp = t >> 8;
  const int wave = t >> 6, lane = t & 63;
  const int bf = detect_bf(xa_w);
  if (t < 8) { int fi = 8 * b + t; if (fi < TOTAL) g_done[fi] = 0; }
  __shared__ float sw[HD];
  __shared__ float sp[4][HD];
  __shared__ float sr[16];
  __shared__ float s_wkT[32][HD + 1];        // Wk^T tile, 32.9 KB, conflict-free
  __shared__ int s_node[TOTAL];              // BFS block only (20 KB)
  if (b < HD) {
    if (grp == 0) sw[col] = ldin(Wq, b * HD + col, bf);
    __syncthreads();
    if (grp == 1) {                              // vq[b] partial (overlapped)
      float pv = sw[col] * ldin(bk, col, bf);
#pragma unroll
      for (int off = 32; off > 0; off >>= 1) pv += __shfl_down(pv, off, 64);
      if (lane == 0) sr[wave] = pv;              // waves 4..7
    }
    if (grp == 2) {                              // WrS row b (overlapped, coalesced)
      float s = 0.f;
#pragma unroll
      for (int q = 0; q < 4; ++q) s += ldin(Wr, (size_t)(q * HD + b) * HD + col, bf);
      g_WrS[b * HD + col] = s;
    }
    // WQK[b][col] = Wq row b . Wk row col, via LDS-staged Wk^T tiles
    float acc0 = 0.f, acc1 = 0.f;
    const int hh = t & 31, r0 = t >> 5;          // staging coords (r0: 0..31)
    for (int h0 = 0; h0 < HD; h0 += 32) {
#pragma unroll
      for (int rr = 0; rr < 8; ++rr) {           // coalesced: hh is the fast axis
        const int row = rr * 32 + r0;
        s_wkT[hh][row] = ldin(Wk, row * HD + h0 + hh, bf);
      }
      __syncthreads();
      const int hb = grp * 8;                    // grp's 8-slice of this tile
#pragma unroll
      for (int i = 0; i < 8; i += 2) {
        acc0 += sw[h0 + hb + i]     * s_wkT[hb + i][col];
        acc1 += sw[h0 + hb + i + 1] * s_wkT[hb + i + 1][col];
      }
      __syncthreads();                           // tile reuse guard
    }
    sp[grp][col] = acc0 + acc1;
    __syncthreads();
    if (grp == 0)
      g_WQK[b * HD + col] = (sp[0][col] + sp[1][col]) + (sp[2][col] + sp[3][col]);
    if (t == 0) g_vq[b] = (sr[4] + sr[5]) + (sr[6] + sr[7]);
  } else if (b == HD) {
    {                                            // ck[col] = Wk row col . bq, split 4
      const int h0 = grp * 64;
      float a0 = 0.f, a1 = 0.f, a2 = 0.f, a3 = 0.f;
      for (int h = 0; h < 64; h += 4) {
        a0 += ldin(Wk, col * HD + h0 + h,     bf) * ldin(bq, h0 + h,     bf);
        a1 += ldin(Wk, col * HD + h0 + h + 1, bf) * ldin(bq, h0 + h + 1, bf);
        a2 += ldin(Wk, col * HD + h0 + h + 2, bf) * ldin(bq, h0 + h + 2, bf);
        a3 += ldin(Wk, col * HD + h0 + h + 3, bf) * ldin(bq, h0 + h + 3, bf);
      }
      sp[grp][col] = (a0 + a1) + (a2 + a3);
    }
    if (grp == 1) {
      float pb = ldin(bq, col, bf) * ldin(bk, col, bf);
#pragma unroll
      for (int off = 32; off > 0; off >>= 1) pb += __shfl_down(pb, off, 64);
      if (lane == 0) sr[wave] = pb;              // waves 4..7
    }
    __syncthreads();
    if (grp == 0)
      g_ck[col] = (sp[0][col] + sp[1][col]) + (sp[2][col] + sp[3][col]);
    if (t == 0) g_bqk = (sr[4] + sr[5]) + (sr[6] + sr[7]);
  } else if (b <= HD + NN) {                     // encode node n, K=FD split 4
    const int n = b - HD - 1;
    if (t < FD) sw[t] = ldin(xa, n * FD + t, bf);
    __syncthreads();
    const int f0 = grp * 32;
    float a0 = 0.f, a1 = 0.f, a2 = 0.f, a3 = 0.f;
    for (int f = 0; f < 32; f += 4) {
      a0 += sw[f0 + f]     * ldin(We, (f0 + f)     * HD + col, bf);
      a1 += sw[f0 + f + 1] * ldin(We, (f0 + f + 1) * HD + col, bf);
      a2 += sw[f0 + f + 2] * ldin(We, (f0 + f + 2) * HD + col, bf);
      a3 += sw[f0 + f + 3] * ldin(We, (f0 + f + 3) * HD + col, bf);
    }
    sp[grp][col] = (a0 + a1) + (a2 + a3);
    __syncthreads();
    if (grp == 0)
      g_hist[(size_t)(n * HIST) * HD + col] =
          ldin(be, col, bf) + (sp[0][col] + sp[1][col]) + (sp[2][col] + sp[3][col]);
  } else {                                       // BFS queue expansion
    if (t == 0) g_dtype = bf;
    bool c8 = (lane < 8) ? (nbrs[2 * lane + 1] == 0) : true;
    unsigned long long im = __ballot(c8);
    const int i64 = ((im & 0xFFull) == 0xFFull) ? 1 : 0;
    if (t == 0) g_i64 = i64;
    const int S = decode_S(dS);
    for (int i = t; i < S; i += 1024) s_node[i] = i;
    __syncthreads();
    int done = S;
    while (done < TOTAL) {                       // message tree, depth ~4
      long long nd = (long long)S + 8LL * (long long)done;
      int new_done = nd > (long long)TOTAL ? TOTAL : (int)nd;
      for (int i = done + t; i < new_done; i += 1024)
        s_node[i] = get_nbr(nbrs, i64, s_node[(i - S) >> 3], (i - S) & 7);
      __syncthreads();
      done = new_done;
    }
    for (int i = t; i < TOTAL; i += 1024) g_node[i] = s_node[i];
  }
}

// ---------------- dataflow executor: ONE BLOCK PER NODE + fused output --------------
// ABLATION (round 12): prefetch machinery REMOVED. History: round-5 body (no
// prefetch) = 300 us; round-8 (+prefetch+hoist+fused-out) = 316 us; round-11
// (+fusion) = 326 us. The prefetch never paid for its per-step overhead. This is
// the round-5 proven step body + register-hoisted invariants + fused projection.
// Residency: 512 blocks, launch_bounds(256,2), ~34 KB LDS -> 2 blocks/CU = all 512
// resident. Deps of entry e have smaller queue index -> progress by induction.
__global__ void __launch_bounds__(256, 2)
k_flow(const void* __restrict__ fmsg, const void* __restrict__ br_,
       const void* __restrict__ Wm, const void* __restrict__ bm,
       const void* __restrict__ Wd, const void* __restrict__ bd,
       void* __restrict__ out, const int* __restrict__ dS) {
  const int n = blockIdx.x;
  const int t = threadIdx.x;
  const int wave = t >> 6, lane = t & 63;
  const int S = decode_S(dS);
  const int bf = g_dtype;
  __shared__ float s_hist[HIST][HD];         // node-n ring buffer, column t private
  __shared__ float s_msg[MD];
  __shared__ float s_vals[HD];
  __shared__ float s_ns[HD];
  __shared__ float s_red[4][HIST + 1];
  __shared__ int   s_list[TOTAL];            // safe upper bound (20 KB)
  __shared__ int   s_cnt;

  // loop invariants in registers
  const float rck = g_ck[t];
  const float rvq = g_vq[t];
  const float rbqk = g_bqk;
  const float rbr = ldin(br_, t, bf);
  const float rbm = ldin(bm, t, bf);

#pragma unroll
  for (int j = 1; j < HIST; ++j) s_hist[j][t] = 0.f;   // invalid slots read as 0
  s_hist[0][t] = finz(g_hist[(size_t)n * HIST * HD + t]);  // encoded state

  if (wave == 0) {                           // build node-n entry list (queue order)
    int k = 0;
    for (int base = 0; base < TOTAL; base += 64) {
      int nd = g_node[base + lane];
      unsigned long long m = __ballot(nd == n);
      if (nd == n) {
        unsigned long long below = m & ((1ull << lane) - 1ull);
        s_list[k + (int)__popcll(below)] = base + lane;
      }
      k += (int)__popcll(m);
    }
    if (lane == 0) s_cnt = k;
  }
  __syncthreads();
  const int cnt = s_cnt;

  for (int k = 0; k < cnt; ++k) {
    const int e = s_list[k];
    const int c = k + 1;
    const int v = (c < HIST) ? c : HIST;
    const int slot = c % HIST;
    const bool hc = (S + 8 * e) < TOTAL;

    // ---- acquire message ----
    float ms;
    if (e < S) {
      ms = ldin(fmsg, e * MD + t, bf);
    } else {
      const int p = (e - S) >> 3;
      if (t == 0)
        while (__hip_atomic_load(&g_done[p], __ATOMIC_RELAXED,
                                 __HIP_MEMORY_SCOPE_AGENT) == 0)
          __builtin_amdgcn_s_sleep(4);
      __syncthreads();                       // flag seen by whole block
      ms = scload(g_msgb + (size_t)p * MD + t);
    }
    s_msg[t] = finz(ms);
    __syncthreads();

    // ---- kq[t] = msg . WQK[:,t] + ck[t] (4-acc, proven scalar walk) ----
    float a0 = 0.f, a1 = 0.f, a2 = 0.f, a3 = 0.f;
    for (int m = 0; m < MD; m += 4) {
      a0 += s_msg[m]     * g_WQK[(m)     * HD + t];
      a1 += s_msg[m + 1] * g_WQK[(m + 1) * HD + t];
      a2 += s_msg[m + 2] * g_WQK[(m + 2) * HD + t];
      a3 += s_msg[m + 3] * g_WQK[(m + 3) * HD + t];
    }
    const float kq = rck + ((a0 + a1) + (a2 + a3));

    // ---- 11 dot-products via wave shuffle + LDS fold ----
    float part[HIST + 1];
#pragma unroll
    for (int j = 0; j < HIST; ++j) part[j] = s_hist[j][t] * kq;
    part[HIST] = s_msg[t] * rvq;
#pragma unroll
    for (int o = 32; o > 0; o >>= 1) {
#pragma unroll
      for (int j = 0; j <= HIST; ++j) part[j] += __shfl_down(part[j], o, 64);
    }
    if (lane == 0) {
#pragma unroll
      for (int j = 0; j <= HIST; ++j) s_red[wave][j] = part[j];
    }
    __syncthreads();

    float sc[HIST + 1];
#pragma unroll
    for (int j = 0; j <= HIST; ++j)
      sc[j] = (s_red[0][j] + s_red[1][j]) + (s_red[2][j] + s_red[3][j]);
    const float bkq = sc[HIST] + rbqk;
    float lg[HIST];
#pragma unroll
    for (int j = 0; j < HIST; ++j)
      lg[j] = (j < v) ? ((sc[j] + bkq) * INV_SQRT_H) : -1e30f;
    float mx = lg[0];
#pragma unroll
    for (int j = 1; j < HIST; ++j) mx = fmaxf(mx, lg[j]);
    float e_[HIST], den = 0.f;
#pragma unroll
    for (int j = 0; j < HIST; ++j) { e_[j] = __expf(lg[j] - mx); den += e_[j]; }
    const float iden = 1.0f / den;
    float val = 0.f;
#pragma unroll
    for (int j = 0; j < HIST; ++j) val += e_[j] * s_hist[j][t];
    s_vals[t] = val * iden;
    __syncthreads();

    // ---- ns = vals @ WrS + br ----
    float b0 = 0.f, b1 = 0.f, b2 = 0.f, b3 = 0.f;
    for (int h = 0; h < HD; h += 4) {
      b0 += s_vals[h]     * g_WrS[(h)     * HD + t];
      b1 += s_vals[h + 1] * g_WrS[(h + 1) * HD + t];
      b2 += s_vals[h + 2] * g_WrS[(h + 2) * HD + t];
      b3 += s_vals[h + 3] * g_WrS[(h + 3) * HD + t];
    }
    const float ns = rbr + ((b0 + b1) + (b2 + b3));
    s_hist[slot][t] = ns;                    // column-private
    if (hc) s_ns[t] = ns;
    __syncthreads();                         // s_ns visible to all waves

    // ---- newmessage = [ns; msg] @ Wm + bm (parents only) ----
    if (hc) {
      float c0 = 0.f, c1 = 0.f, c2 = 0.f, c3 = 0.f;
      if (bf) {
        const bf16* w = (const bf16*)Wm;
        for (int h = 0; h < HD; h += 4) {
          c0 += s_ns[h]     * __bfloat162float(w[(h)     * MD + t]);
          c1 += s_ns[h + 1] * __bfloat162float(w[(h + 1) * MD + t]);
          c2 += s_ns[h + 2] * __bfloat162float(w[(h + 2) * MD + t]);
          c3 += s_ns[h + 3] * __bfloat162float(w[(h + 3) * MD + t]);
        }
        for (int m = 0; m < MD; m += 4) {
          c0 += s_msg[m]     * __bfloat162float(w[(HD + m)     * MD + t]);
          c1 += s_msg[m + 1] * __bfloat162float(w[(HD + m + 1) * MD + t]);
          c2 += s_msg[m + 2] * __bfloat162float(w[(HD + m + 2) * MD + t]);
          c3 += s_msg[m + 3] * __bfloat162float(w[(HD + m + 3) * MD + t]);
        }
      } else {
        const float* w = (const float*)Wm;
        for (int h = 0; h < HD; h += 4) {
          c0 += s_ns[h]     * w[(h)     * MD + t];
          c1 += s_ns[h + 1] * w[(h + 1) * MD + t];
          c2 += s_ns[h + 2] * w[(h + 2) * MD + t];
          c3 += s_ns[h + 3] * w[(h + 3) * MD + t];
        }
        for (int m = 0; m < MD; m += 4) {
          c0 += s_msg[m]     * w[(HD + m)     * MD + t];
          c1 += s_msg[m + 1] * w[(HD + m + 1) * MD + t];
          c2 += s_msg[m + 2] * w[(HD + m + 2) * MD + t];
          c3 += s_msg[m + 3] * w[(HD + m + 3) * MD + t];
        }
      }
      scstore(&g_msgb[(size_t)e * MD + t], rbm + ((c0 + c1) + (c2 + c3)));
      asm volatile("s_waitcnt vmcnt(0)" ::: "memory");   // own store at coherence pt
    }
    __syncthreads();                         // stores drained + LDS reuse guard
    if (hc && t == 0)
      __hip_atomic_store(&g_done[e], 1, __ATOMIC_RELAXED,
                         __HIP_MEMORY_SCOPE_AGENT);
  }

  // ---- fused final projection + log_softmax (threads 0..127: pp = t>>6, o = t&63) --
  const int slotF = cnt % HIST;
  if (t < PD * OD) {
    const int pp = t >> 6, o = t & 63;
    float acc = finz(ldin(bd, pp * OD + o, bf));
    for (int h = 0; h < HD; ++h)
      acc += finz(s_hist[slotF][h]) * ldin(Wd, (pp * HD + h) * OD + o, bf);
    acc = finz(acc);
    float mx = acc;
#pragma unroll
    for (int off = 32; off > 0; off >>= 1) mx = fmaxf(mx, __shfl_xor(mx, off, 64));
    float ex = __expf(acc - mx);
    float s = ex;
#pragma unroll
    for (int off = 32; off > 0; off >>= 1) s += __shfl_xor(s, off, 64);
    float r = finz(acc - mx - logf(s));
    const int oi = (pp * NN + n) * OD + o;
    if (bf) ((bf16*)out)[oi] = __float2bfloat16(r);
    else    ((float*)out)[oi] = r;
  }
}

extern "C" void kernel_launch(void* const* d_in, const int* in_sizes, int n_in,
                              void* d_out, int out_size, void* d_ws, size_t ws_size,
                              hipStream_t stream) {
  const void* xa   = d_in[0];
  const int*  nbrs = (const int*)d_in[1];
  const void* fmsg = d_in[2];
  const void* We   = d_in[3];
  const void* be   = d_in[4];
  const void* Wq   = d_in[5];
  const void* bq   = d_in[6];
  const void* Wk   = d_in[7];
  const void* bk   = d_in[8];
  const void* Wr   = d_in[9];
  const void* br   = d_in[10];
  const void* Wm   = d_in[11];
  const void* bm   = d_in[12];
  const void* Wd   = d_in[13];
  const void* bd   = d_in[14];
  const int*  dS   = (const int*)d_in[15];
  (void)d_ws; (void)ws_size; (void)in_sizes; (void)n_in; (void)out_size;

  k_prep<<<dim3(HD + 1 + NN + 1), dim3(1024), 0, stream>>>(
      xa, (const unsigned*)xa, nbrs, dS, We, be, Wq, Wk, Wr, bq, bk);
  k_flow<<<dim3(NN), dim3(256), 0, stream>>>(fmsg, br, Wm, bm, Wd, bd, d_out, dS);
}

// Round 13
// 433.987 us; speedup vs baseline: 1.0287x; 1.0087x over previous
//
#include <hip/hip_runtime.h>
#include <hip/hip_bf16.h>

#define NN 512
#define DEG 8
#define FD 128
#define HD 256
#define MD 256
#define OD 64
#define PD 2
#define HIST 10
#define TOTAL (10 * NN)       /* 5120 queue entries processed */
#define NPAR 648              /* entries with children: i < (TOTAL-S)/8 <= 632 */
#define INV_SQRT_H 0.0625f

typedef __hip_bfloat16 bf16;

// bit-level finite guard (fast-math-proof)
__device__ __forceinline__ float finz(float x) {
  unsigned u = __float_as_uint(x);
  return (((u >> 23) & 0xFFu) == 0xFFu) ? 0.f : x;
}

// runtime-dtype load: bf=1 -> bf16 array, bf=0 -> float array
__device__ __forceinline__ float ldin(const void* p, int idx, int bf) {
  if (bf) return __bfloat162float(((const bf16*)p)[idx]);
  return ((const float*)p)[idx];
}

// device-coherent dword load/store (relaxed agent atomics -> flagged global op,
// bypasses non-coherent L2 for THIS access only; no cache-wide fences anywhere)
__device__ __forceinline__ float scload(const float* p) {
  return __uint_as_float(__hip_atomic_load((const unsigned*)p, __ATOMIC_RELAXED,
                                           __HIP_MEMORY_SCOPE_AGENT));
}
__device__ __forceinline__ void scstore(float* p, float v) {
  __hip_atomic_store((unsigned*)p, __float_as_uint(v), __ATOMIC_RELAXED,
                     __HIP_MEMORY_SCOPE_AGENT);
}

// ---- static device scratch ----
__device__ float g_hist[NN * HIST * HD];    // slot-0 encoded states (k_prep -> k_flow)
__device__ float g_msgb[NPAR * MD];         // messages of entries with children
__device__ float g_WQK[HD * HD];            // Wq @ Wk^T   (kq = msg.WQK + ck)
__device__ float g_WrS[HD * HD];            // sum of 4 Wr row-blocks
__device__ float g_vq[HD];                  // Wq @ bk
__device__ float g_ck[HD];                  // Wk @ bq
__device__ float g_bqk;                     // bq . bk
__device__ int   g_node[TOTAL];
__device__ int   g_done[TOTAL];             // message-ready flags (parents only)
__device__ int   g_dtype;                   // 1 = float tensors are bf16
__device__ int   g_i64;                     // 1 = neighbors int64

__device__ __forceinline__ int decode_S(const int* dS) {
  int r = dS[0];
  if (r >= 1 && r <= NN) return r;
  float f = __int_as_float(r);
  if (f >= 1.f && f <= (float)NN) return (int)f;
  unsigned u = ((unsigned)r & 0xFFFFu) << 16;
  float g = __uint_as_float(u);
  if (g >= 1.f && g <= (float)NN) return (int)g;
  return 64;
}

__device__ __forceinline__ int get_nbr(const int* nbrs, int i64, int n, int d) {
  int v = i64 ? nbrs[2 * (n * DEG + d)] : nbrs[n * DEG + d];
  return (v < 0) ? 0 : (v >= NN ? NN - 1 : v);
}

// wave-parallel dtype probe: same predicate as the validated serial version,
// one ballot over the first 64 words instead of 64 serial loads.
__device__ __forceinline__ int detect_bf(const unsigned* xa_w) {
  const int lane = threadIdx.x & 63;
  unsigned lo = xa_w[lane] & 0xFFFFu;
  float av = fabsf(__uint_as_float(lo << 16));
  unsigned long long m = __ballot(av > 0.000244140625f && av < 64.f);
  return ((int)__popcll(m) >= 32) ? 1 : 0;
}

// ---------------- k_prep: 98 blocks, ONE scheduling round -------------------------
// blocks 0..31: 8 WQK rows + 8 WrS rows + 8 vq entries each (Wk tile staged once,
//               reused for 8 rows -> 8x less Wk traffic than 1-row blocks);
// block 32:     ck (LDS-staged Wk, coalesced) + bqk;
// blocks 33..96: encode 8 nodes each (We loads reused across 8 nodes in registers);
// block 97:     BFS queue expansion.
// 98 blocks <= 256 CUs => all concurrent; makespan = slowest single block.
__global__ void __launch_bounds__(1024)
k_prep(const void* __restrict__ xa, const unsigned* __restrict__ xa_w,
       const int* __restrict__ nbrs, const int* __restrict__ dS,
       const void* __restrict__ We, const void* __restrict__ be,
       const void* __restrict__ Wq, const void* __restrict__ Wk,
       const void* __restrict__ Wr, const void* __restrict__ bq,
       const void* __restrict__ bk) {
  const int b = blockIdx.x, t = threadIdx.x;
  const int col = t & 255, grp = t >> 8;
  const int wave = t >> 6, lane = t & 63;
  const int bf = detect_bf(xa_w);
  { int fi = b * 1024 + t; if (fi < TOTAL) g_done[fi] = 0; }   // blocks 0..4 cover
  __shared__ float sw8[8][HD];               // 8 KB   (Wq rows)
  __shared__ float s_wkT[32][HD + 1];        // 32.9 KB (Wk^T tile, conflict-free)
  __shared__ float sp[4][8][HD];             // 32 KB  (grp partials)
  __shared__ float s_xa[8][FD];              // 4 KB   (xa rows)
  __shared__ int   s_node[TOTAL];            // 20 KB  (BFS)
  if (b < 32) {
    const int R = 8 * b;                         // row base
    {                                            // load 8 Wq rows (2 elems/thread)
      const int i0 = t, i1 = t + 1024;
      sw8[i0 >> 8][i0 & 255] = ldin(Wq, (R + (i0 >> 8)) * HD + (i0 & 255), bf);
      sw8[i1 >> 8][i1 & 255] = ldin(Wq, (R + (i1 >> 8)) * HD + (i1 & 255), bf);
    }
    __syncthreads();
    {                                            // WrS rows R..R+7 (2 rows per grp)
      const int r0 = R + 2 * grp, r1 = r0 + 1;
      float s0 = 0.f, s1 = 0.f;
#pragma unroll
      for (int q = 0; q < 4; ++q) {
        s0 += ldin(Wr, (size_t)(q * HD + r0) * HD + col, bf);
        s1 += ldin(Wr, (size_t)(q * HD + r1) * HD + col, bf);
      }
      g_WrS[(size_t)r0 * HD + col] = s0;
      g_WrS[(size_t)r1 * HD + col] = s1;
    }
    if (wave < 8) {                              // vq rows R..R+7 (one wave per row)
      float pv = 0.f;
#pragma unroll
      for (int j = 0; j < 4; ++j)
        pv += sw8[wave][lane + 64 * j] * ldin(bk, lane + 64 * j, bf);
#pragma unroll
      for (int off = 32; off > 0; off >>= 1) pv += __shfl_down(pv, off, 64);
      if (lane == 0) g_vq[R + wave] = pv;
    }
    // WQK rows R..R+7 via staged Wk^T tiles (tile reused for all 8 rows)
    float q0 = 0.f, q1 = 0.f, q2 = 0.f, q3 = 0.f;
    float q4 = 0.f, q5 = 0.f, q6 = 0.f, q7 = 0.f;
    const int hh = t & 31, r0s = t >> 5;         // staging coords
    const int hb = grp * 8;                      // grp's 8-slice
    for (int h0 = 0; h0 < HD; h0 += 32) {
#pragma unroll
      for (int rr = 0; rr < 8; ++rr) {           // coalesced: hh is the fast axis
        const int row = rr * 32 + r0s;
        s_wkT[hh][row] = ldin(Wk, row * HD + h0 + hh, bf);
      }
      __syncthreads();
#pragma unroll
      for (int i = 0; i < 8; ++i) {
        const float wk = s_wkT[hb + i][col];
        const int h = h0 + hb + i;
        q0 += sw8[0][h] * wk; q1 += sw8[1][h] * wk;
        q2 += sw8[2][h] * wk; q3 += sw8[3][h] * wk;
        q4 += sw8[4][h] * wk; q5 += sw8[5][h] * wk;
        q6 += sw8[6][h] * wk; q7 += sw8[7][h] * wk;
      }
      __syncthreads();                           // tile reuse guard
    }
    sp[grp][0][col] = q0; sp[grp][1][col] = q1;
    sp[grp][2][col] = q2; sp[grp][3][col] = q3;
    sp[grp][4][col] = q4; sp[grp][5][col] = q5;
    sp[grp][6][col] = q6; sp[grp][7][col] = q7;
    __syncthreads();
    if (grp == 0) {
#pragma unroll
      for (int r = 0; r < 8; ++r)
        g_WQK[(size_t)(R + r) * HD + col] =
            (sp[0][r][col] + sp[1][r][col]) + (sp[2][r][col] + sp[3][r][col]);
    }
  } else if (b == 32) {                          // ck (staged, coalesced) + bqk
    float ca = 0.f;
    const int hh = t & 31, r0s = t >> 5;
    const int hb = grp * 8;
    for (int h0 = 0; h0 < HD; h0 += 32) {
#pragma unroll
      for (int rr = 0; rr < 8; ++rr) {
        const int row = rr * 32 + r0s;
        s_wkT[hh][row] = ldin(Wk, row * HD + h0 + hh, bf);
      }
      __syncthreads();
#pragma unroll
      for (int i = 0; i < 8; ++i)
        ca += ldin(bq, h0 + hb + i, bf) * s_wkT[hb + i][col];
      __syncthreads();
    }
    sp[grp][0][col] = ca;
    __syncthreads();
    if (grp == 0)
      g_ck[col] = (sp[0][0][col] + sp[1][0][col]) + (sp[2][0][col] + sp[3][0][col]);
    if (wave == 0) {
      float pb = 0.f;
#pragma unroll
      for (int j = 0; j < 4; ++j)
        pb += ldin(bq, lane + 64 * j, bf) * ldin(bk, lane + 64 * j, bf);
#pragma unroll
      for (int off = 32; off > 0; off >>= 1) pb += __shfl_down(pb, off, 64);
      if (lane == 0) g_bqk = pb;
    }
  } else if (b <= 96) {                          // encode nodes n0..n0+7
    const int n0 = (b - 33) * 8;
    {                                            // stage 8 xa rows (1 elem/thread)
      const int r = t >> 7, f = t & 127;
      s_xa[r][f] = ldin(xa, (n0 + r) * FD + f, bf);
    }
    __syncthreads();
    float e0 = 0.f, e1 = 0.f, e2 = 0.f, e3 = 0.f;
    float e4 = 0.f, e5 = 0.f, e6 = 0.f, e7 = 0.f;
    const int f0 = grp * 32;                     // grp's f-slice
    for (int f = 0; f < 32; ++f) {
      const float we = ldin(We, (f0 + f) * HD + col, bf);  // reused by 8 nodes
      e0 += s_xa[0][f0 + f] * we; e1 += s_xa[1][f0 + f] * we;
      e2 += s_xa[2][f0 + f] * we; e3 += s_xa[3][f0 + f] * we;
      e4 += s_xa[4][f0 + f] * we; e5 += s_xa[5][f0 + f] * we;
      e6 += s_xa[6][f0 + f] * we; e7 += s_xa[7][f0 + f] * we;
    }
    sp[grp][0][col] = e0; sp[grp][1][col] = e1;
    sp[grp][2][col] = e2; sp[grp][3][col] = e3;
    sp[grp][4][col] = e4; sp[grp][5][col] = e5;
    sp[grp][6][col] = e6; sp[grp][7][col] = e7;
    __syncthreads();
    if (grp == 0) {
      const float be_ = ldin(be, col, bf);
#pragma unroll
      for (int r = 0; r < 8; ++r)
        g_hist[(size_t)((n0 + r) * HIST) * HD + col] =
            be_ + (sp[0][r][col] + sp[1][r][col]) + (sp[2][r][col] + sp[3][r][col]);
    }
  } else {                                       // BFS queue expansion
    if (t == 0) g_dtype = bf;
    bool c8 = (lane < 8) ? (nbrs[2 * lane + 1] == 0) : true;
    unsigned long long im = __ballot(c8);
    const int i64 = ((im & 0xFFull) == 0xFFull) ? 1 : 0;
    if (t == 0) g_i64 = i64;
    const int S = decode_S(dS);
    for (int i = t; i < S; i += 1024) s_node[i] = i;
    __syncthreads();
    int done = S;
    while (done < TOTAL) {                       // message tree, depth ~4
      long long nd = (long long)S + 8LL * (long long)done;
      int new_done = nd > (long long)TOTAL ? TOTAL : (int)nd;
      for (int i = done + t; i < new_done; i += 1024)
        s_node[i] = get_nbr(nbrs, i64, s_node[(i - S) >> 3], (i - S) & 7);
      __syncthreads();
      done = new_done;
    }
    for (int i = t; i < TOTAL; i += 1024) g_node[i] = s_node[i];
  }
}

// ---------------- dataflow executor: ONE BLOCK PER NODE + fused output --------------
// BYTE-IDENTICAL to round 12 (measured 315-320 us, 52 VGPR, FETCH ~7 MB): round-5
// proven scalar step body + register-hoisted invariants + fused final projection.
// Residency: 512 blocks, launch_bounds(256,2), ~34 KB LDS -> 2 blocks/CU = all 512
// resident. Deps of entry e have smaller queue index -> progress by induction.
__global__ void __launch_bounds__(256, 2)
k_flow(const void* __restrict__ fmsg, const void* __restrict__ br_,
       const void* __restrict__ Wm, const void* __restrict__ bm,
       const void* __restrict__ Wd, const void* __restrict__ bd,
       void* __restrict__ out, const int* __restrict__ dS) {
  const int n = blockIdx.x;
  const int t = threadIdx.x;
  const int wave = t >> 6, lane = t & 63;
  const int S = decode_S(dS);
  const int bf = g_dtype;
  __shared__ float s_hist[HIST][HD];         // node-n ring buffer, column t private
  __shared__ float s_msg[MD];
  __shared__ float s_vals[HD];
  __shared__ float s_ns[HD];
  __shared__ float s_red[4][HIST + 1];
  __shared__ int   s_list[TOTAL];            // safe upper bound (20 KB)
  __shared__ int   s_cnt;

  // loop invariants in registers
  const float rck = g_ck[t];
  const float rvq = g_vq[t];
  const float rbqk = g_bqk;
  const float rbr = ldin(br_, t, bf);
  const float rbm = ldin(bm, t, bf);

#pragma unroll
  for (int j = 1; j < HIST; ++j) s_hist[j][t] = 0.f;   // invalid slots read as 0
  s_hist[0][t] = finz(g_hist[(size_t)n * HIST * HD + t]);  // encoded state

  if (wave == 0) {                           // build node-n entry list (queue order)
    int k = 0;
    for (int base = 0; base < TOTAL; base += 64) {
      int nd = g_node[base + lane];
      unsigned long long m = __ballot(nd == n);
      if (nd == n) {
        unsigned long long below = m & ((1ull << lane) - 1ull);
        s_list[k + (int)__popcll(below)] = base + lane;
      }
      k += (int)__popcll(m);
    }
    if (lane == 0) s_cnt = k;
  }
  __syncthreads();
  const int cnt = s_cnt;

  for (int k = 0; k < cnt; ++k) {
    const int e = s_list[k];
    const int c = k + 1;
    const int v = (c < HIST) ? c : HIST;
    const int slot = c % HIST;
    const bool hc = (S + 8 * e) < TOTAL;

    // ---- acquire message ----
    float ms;
    if (e < S) {
      ms = ldin(fmsg, e * MD + t, bf);
    } else {
      const int p = (e - S) >> 3;
      if (t == 0)
        while (__hip_atomic_load(&g_done[p], __ATOMIC_RELAXED,
                                 __HIP_MEMORY_SCOPE_AGENT) == 0)
          __builtin_amdgcn_s_sleep(4);
      __syncthreads();                       // flag seen by whole block
      ms = scload(g_msgb + (size_t)p * MD + t);
    }
    s_msg[t] = finz(ms);
    __syncthreads();

    // ---- kq[t] = msg . WQK[:,t] + ck[t] (4-acc, proven scalar walk) ----
    float a0 = 0.f, a1 = 0.f, a2 = 0.f, a3 = 0.f;
    for (int m = 0; m < MD; m += 4) {
      a0 += s_msg[m]     * g_WQK[(m)     * HD + t];
      a1 += s_msg[m + 1] * g_WQK[(m + 1) * HD + t];
      a2 += s_msg[m + 2] * g_WQK[(m + 2) * HD + t];
      a3 += s_msg[m + 3] * g_WQK[(m + 3) * HD + t];
    }
    const float kq = rck + ((a0 + a1) + (a2 + a3));

    // ---- 11 dot-products via wave shuffle + LDS fold ----
    float part[HIST + 1];
#pragma unroll
    for (int j = 0; j < HIST; ++j) part[j] = s_hist[j][t] * kq;
    part[HIST] = s_msg[t] * rvq;
#pragma unroll
    for (int o = 32; o > 0; o >>= 1) {
#pragma unroll
      for (int j = 0; j <= HIST; ++j) part[j] += __shfl_down(part[j], o, 64);
    }
    if (lane == 0) {
#pragma unroll
      for (int j = 0; j <= HIST; ++j) s_red[wave][j] = part[j];
    }
    __syncthreads();

    float sc[HIST + 1];
#pragma unroll
    for (int j = 0; j <= HIST; ++j)
      sc[j] = (s_red[0][j] + s_red[1][j]) + (s_red[2][j] + s_red[3][j]);
    const float bkq = sc[HIST] + rbqk;
    float lg[HIST];
#pragma unroll
    for (int j = 0; j < HIST; ++j)
      lg[j] = (j < v) ? ((sc[j] + bkq) * INV_SQRT_H) : -1e30f;
    float mx = lg[0];
#pragma unroll
    for (int j = 1; j < HIST; ++j) mx = fmaxf(mx, lg[j]);
    float e_[HIST], den = 0.f;
#pragma unroll
    for (int j = 0; j < HIST; ++j) { e_[j] = __expf(lg[j] - mx); den += e_[j]; }
    const float iden = 1.0f / den;
    float val = 0.f;
#pragma unroll
    for (int j = 0; j < HIST; ++j) val += e_[j] * s_hist[j][t];
    s_vals[t] = val * iden;
    __syncthreads();

    // ---- ns = vals @ WrS + br ----
    float b0 = 0.f, b1 = 0.f, b2 = 0.f, b3 = 0.f;
    for (int h = 0; h < HD; h += 4) {
      b0 += s_vals[h]     * g_WrS[(h)     * HD + t];
      b1 += s_vals[h + 1] * g_WrS[(h + 1) * HD + t];
      b2 += s_vals[h + 2] * g_WrS[(h + 2) * HD + t];
      b3 += s_vals[h + 3] * g_WrS[(h + 3) * HD + t];
    }
    const float ns = rbr + ((b0 + b1) + (b2 + b3));
    s_hist[slot][t] = ns;                    // column-private
    if (hc) s_ns[t] = ns;
    __syncthreads();                         // s_ns visible to all waves

    // ---- newmessage = [ns; msg] @ Wm + bm (parents only) ----
    if (hc) {
      float c0 = 0.f, c1 = 0.f, c2 = 0.f, c3 = 0.f;
      if (bf) {
        const bf16* w = (const bf16*)Wm;
        for (int h = 0; h < HD; h += 4) {
          c0 += s_ns[h]     * __bfloat162float(w[(h)     * MD + t]);
          c1 += s_ns[h + 1] * __bfloat162float(w[(h + 1) * MD + t]);
          c2 += s_ns[h + 2] * __bfloat162float(w[(h + 2) * MD + t]);
          c3 += s_ns[h + 3] * __bfloat162float(w[(h + 3) * MD + t]);
        }
        for (int m = 0; m < MD; m += 4) {
          c0 += s_msg[m]     * __bfloat162float(w[(HD + m)     * MD + t]);
          c1 += s_msg[m + 1] * __bfloat162float(w[(HD + m + 1) * MD + t]);
          c2 += s_msg[m + 2] * __bfloat162float(w[(HD + m + 2) * MD + t]);
          c3 += s_msg[m + 3] * __bfloat162float(w[(HD + m + 3) * MD + t]);
        }
      } else {
        const float* w = (const float*)Wm;
        for (int h = 0; h < HD; h += 4) {
          c0 += s_ns[h]     * w[(h)     * MD + t];
          c1 += s_ns[h + 1] * w[(h + 1) * MD + t];
          c2 += s_ns[h + 2] * w[(h + 2) * MD + t];
          c3 += s_ns[h + 3] * w[(h + 3) * MD + t];
        }
        for (int m = 0; m < MD; m += 4) {
          c0 += s_msg[m]     * w[(HD + m)     * MD + t];
          c1 += s_msg[m + 1] * w[(HD + m + 1) * MD + t];
          c2 += s_msg[m + 2] * w[(HD + m + 2) * MD + t];
          c3 += s_msg[m + 3] * w[(HD + m + 3) * MD + t];
        }
      }
      scstore(&g_msgb[(size_t)e * MD + t], rbm + ((c0 + c1) + (c2 + c3)));
      asm volatile("s_waitcnt vmcnt(0)" ::: "memory");   // own store at coherence pt
    }
    __syncthreads();                         // stores drained + LDS reuse guard
    if (hc && t == 0)
      __hip_atomic_store(&g_done[e], 1, __ATOMIC_RELAXED,
                         __HIP_MEMORY_SCOPE_AGENT);
  }

  // ---- fused final projection + log_softmax (threads 0..127: pp = t>>6, o = t&63) --
  const int slotF = cnt % HIST;
  if (t < PD * OD) {
    const int pp = t >> 6, o = t & 63;
    float acc = finz(ldin(bd, pp * OD + o, bf));
    for (int h = 0; h < HD; ++h)
      acc += finz(s_hist[slotF][h]) * ldin(Wd, (pp * HD + h) * OD + o, bf);
    acc = finz(acc);
    float mx = acc;
#pragma unroll
    for (int off = 32; off > 0; off >>= 1) mx = fmaxf(mx, __shfl_xor(mx, off, 64));
    float ex = __expf(acc - mx);
    float s = ex;
#pragma unroll
    for (int off = 32; off > 0; off >>= 1) s += __shfl_xor(s, off, 64);
    float r = finz(acc - mx - logf(s));
    const int oi = (pp * NN + n) * OD + o;
    if (bf) ((bf16*)out)[oi] = __float2bfloat16(r);
    else    ((float*)out)[oi] = r;
  }
}

extern "C" void kernel_launch(void* const* d_in, const int* in_sizes, int n_in,
                              void* d_out, int out_size, void* d_ws, size_t ws_size,
                              hipStream_t stream) {
  const void* xa   = d_in[0];
  const int*  nbrs = (const int*)d_in[1];
  const void* fmsg = d_in[2];
  const void* We   = d_in[3];
  const void* be   = d_in[4];
  const void* Wq   = d_in[5];
  const void* bq   = d_in[6];
  const void* Wk   = d_in[7];
  const void* bk   = d_in[8];
  const void* Wr   = d_in[9];
  const void* br   = d_in[10];
  const void* Wm   = d_in[11];
  const void* bm   = d_in[12];
  const void* Wd   = d_in[13];
  const void* bd   = d_in[14];
  const int*  dS   = (const int*)d_in[15];
  (void)d_ws; (void)ws_size; (void)in_sizes; (void)n_in; (void)out_size;

  k_prep<<<dim3(98), dim3(1024), 0, stream>>>(
      xa, (const unsigned*)xa, nbrs, dS, We, be, Wq, Wk, Wr, bq, bk);
  k_flow<<<dim3(NN), dim3(256), 0, stream>>>(fmsg, br, Wm, bm, Wd, bd, d_out, dS);
}